// Round 1
// baseline (349.689 us; speedup 1.0000x reference)
//
#include <hip/hip_runtime.h>
#include <hip/hip_bf16.h>

#define NROWS 8192   // N == M == 8192
#define DDIM  512
#define OUTN  8192

typedef short bf16x8 __attribute__((ext_vector_type(8)));  // 8 bf16 = 4 VGPRs
typedef float f32x4  __attribute__((ext_vector_type(4)));

__device__ __forceinline__ void gload_lds16(const void* g, void* l) {
    __builtin_amdgcn_global_load_lds(
        (const __attribute__((address_space(1))) void*)g,
        (__attribute__((address_space(3))) void*)l, 16, 0, 0);
}

// ---------------------------------------------------------------------------
// Prepass: fp32 -> bf16 (RNE) + per-row squared norms. One wave per row;
// rows 0..8191 -> x, rows 8192..16383 -> y.
// ---------------------------------------------------------------------------
__global__ void __launch_bounds__(256)
rbf_prep(const float* __restrict__ x, const float* __restrict__ y,
         unsigned short* __restrict__ xb, unsigned short* __restrict__ yb,
         float* __restrict__ x2, float* __restrict__ y2) {
    int wave = (blockIdx.x * blockDim.x + threadIdx.x) >> 6;  // 0..16383
    int lane = threadIdx.x & 63;

    const float* src;
    unsigned short* dst;
    float* nrm;
    int row;
    if (wave < NROWS) { src = x; dst = xb; nrm = x2; row = wave; }
    else              { src = y; dst = yb; nrm = y2; row = wave - NROWS; }

    const float* p = src + (size_t)row * DDIM;
    unsigned short* q = dst + (size_t)row * DDIM;

    float s = 0.f;
#pragma unroll
    for (int it = 0; it < 4; ++it) {
        int idx = it * 128 + lane * 2;
        float2 v = *(const float2*)(p + idx);
        s += v.x * v.x + v.y * v.y;
        unsigned int ux = __float_as_uint(v.x);
        unsigned int uy = __float_as_uint(v.y);
        ux = (ux + 0x7fffu + ((ux >> 16) & 1u)) >> 16;   // RNE to bf16
        uy = (uy + 0x7fffu + ((uy >> 16) & 1u)) >> 16;
        *(unsigned int*)(q + idx) = ux | (uy << 16);
    }
#pragma unroll
    for (int off = 32; off > 0; off >>= 1) s += __shfl_down(s, off, 64);
    if (lane == 0) nrm[row] = s;
}

// ---------------------------------------------------------------------------
// Fused GEMM + RBF epilogue. 128x128 block tile, BK=32, 4 waves (2x2),
// each wave 4x4 of 16x16x32 bf16 MFMA. m97-style global_load_lds staging.
// ---------------------------------------------------------------------------
__global__ void __launch_bounds__(256)
rbf_gemm(const unsigned short* __restrict__ xb,
         const unsigned short* __restrict__ yb,
         const float* __restrict__ x2, const float* __restrict__ y2,
         const float* __restrict__ gamma, float* __restrict__ out) {
    __shared__ unsigned short As[128 * 32];
    __shared__ unsigned short Bs[128 * 32];

    const int tid  = threadIdx.x;
    const int lane = tid & 63;
    const int w    = tid >> 6;        // wave 0..3
    const int wm   = w & 1;           // wave row (0..1)
    const int wn   = w >> 1;          // wave col (0..1)

    const int bm = blockIdx.x & 63;
    const int bn = blockIdx.x >> 6;
    const int row0 = bm * 128;
    const int col0 = bn * 128;

    f32x4 acc[4][4] = {};

    // staging address components (per lane)
    const int srow = lane >> 2;          // 0..15 (row within 16-row group)
    const int skc  = (lane & 3) * 8;     // k-offset in elements: 0,8,16,24

    for (int k0 = 0; k0 < DDIM; k0 += 32) {
        // stage A tile: 128 rows x 32 k  (each wave: 2 groups of 16 rows)
#pragma unroll
        for (int i = 0; i < 2; ++i) {
            int rg = w * 32 + i * 16;                       // wave-uniform row group
            const unsigned short* gp =
                xb + (size_t)(row0 + rg + srow) * DDIM + k0 + skc;
            gload_lds16(gp, As + rg * 32);                  // lane L -> base + L*16B
        }
#pragma unroll
        for (int i = 0; i < 2; ++i) {
            int rg = w * 32 + i * 16;
            const unsigned short* gp =
                yb + (size_t)(col0 + rg + srow) * DDIM + k0 + skc;
            gload_lds16(gp, Bs + rg * 32);
        }
        __syncthreads();

        bf16x8 af[4], bfr[4];
#pragma unroll
        for (int mi = 0; mi < 4; ++mi)
            af[mi] = *(const bf16x8*)(As + (wm * 64 + mi * 16 + (lane & 15)) * 32
                                         + (lane >> 4) * 8);
#pragma unroll
        for (int ni = 0; ni < 4; ++ni)
            bfr[ni] = *(const bf16x8*)(Bs + (wn * 64 + ni * 16 + (lane & 15)) * 32
                                          + (lane >> 4) * 8);
#pragma unroll
        for (int mi = 0; mi < 4; ++mi)
#pragma unroll
            for (int ni = 0; ni < 4; ++ni)
                acc[mi][ni] = __builtin_amdgcn_mfma_f32_16x16x32_bf16(
                    af[mi], bfr[ni], acc[mi][ni], 0, 0, 0);
        __syncthreads();
    }

    // Epilogue: out[r][c] = exp(-g * (x2[r] + y2[c] - 2*xy))
    const float g = gamma[0];
#pragma unroll
    for (int mi = 0; mi < 4; ++mi) {
        const int rbase = row0 + wm * 64 + mi * 16 + (lane >> 4) * 4;
        float xn[4];
#pragma unroll
        for (int r = 0; r < 4; ++r) xn[r] = x2[rbase + r];
#pragma unroll
        for (int ni = 0; ni < 4; ++ni) {
            const int col = col0 + wn * 64 + ni * 16 + (lane & 15);
            const float yn = y2[col];
            float* op = out + (size_t)rbase * OUTN + col;
#pragma unroll
            for (int r = 0; r < 4; ++r) {
                float s = xn[r] + yn - 2.0f * acc[mi][ni][r];
                op[(size_t)r * OUTN] = __expf(-g * s);
            }
        }
    }
}

extern "C" void kernel_launch(void* const* d_in, const int* in_sizes, int n_in,
                              void* d_out, int out_size, void* d_ws, size_t ws_size,
                              hipStream_t stream) {
    const float* x     = (const float*)d_in[0];
    const float* y     = (const float*)d_in[1];
    const float* gamma = (const float*)d_in[2];
    float* out = (float*)d_out;

    // workspace layout: xb (8 MB) | yb (8 MB) | x2 (32 KB) | y2 (32 KB)
    char* ws = (char*)d_ws;
    unsigned short* xb = (unsigned short*)ws;
    unsigned short* yb = (unsigned short*)(ws + (size_t)NROWS * DDIM * 2);
    float* x2 = (float*)(ws + (size_t)NROWS * DDIM * 4);
    float* y2 = (float*)(ws + (size_t)NROWS * DDIM * 4 + NROWS * 4);

    // prepass: 16384 waves, 4 waves/block
    rbf_prep<<<4096, 256, 0, stream>>>(x, y, xb, yb, x2, y2);

    // gemm: 64x64 blocks of 128x128
    rbf_gemm<<<4096, 256, 0, stream>>>(xb, yb, x2, y2, gamma, out);
}

// Round 2
// 323.446 us; speedup vs baseline: 1.0811x; 1.0811x over previous
//
#include <hip/hip_runtime.h>

#define NROWS 8192   // N == M == 8192
#define DDIM  512
#define OUTN  8192

typedef int   i32x4 __attribute__((ext_vector_type(4)));
typedef int   i32x8 __attribute__((ext_vector_type(8)));
typedef float f32x4 __attribute__((ext_vector_type(4)));

__device__ __forceinline__ void gload_lds16(const void* g, void* l) {
    __builtin_amdgcn_global_load_lds(
        (const __attribute__((address_space(1))) void*)g,
        (__attribute__((address_space(3))) void*)l, 16, 0, 0);
}

// ---------------------------------------------------------------------------
// Prepass: fp32 -> fp8 e4m3 (OCP, RNE via v_cvt_pk_fp8_f32) + fp32 row sq-norms.
// One wave per row; rows 0..8191 -> x, 8192..16383 -> y. Lane covers 8 elems.
// ---------------------------------------------------------------------------
__global__ void __launch_bounds__(256)
rbf_prep(const float* __restrict__ x, const float* __restrict__ y,
         unsigned char* __restrict__ xb, unsigned char* __restrict__ yb,
         float* __restrict__ x2, float* __restrict__ y2) {
    int wave = (blockIdx.x * blockDim.x + threadIdx.x) >> 6;  // 0..16383
    int lane = threadIdx.x & 63;

    const float* src;
    unsigned char* dst;
    float* nrm;
    int row;
    if (wave < NROWS) { src = x; dst = xb; nrm = x2; row = wave; }
    else              { src = y; dst = yb; nrm = y2; row = wave - NROWS; }

    const float* p = src + (size_t)row * DDIM + lane * 8;
    float4 v0 = *(const float4*)(p);
    float4 v1 = *(const float4*)(p + 4);

    float s = v0.x * v0.x + v0.y * v0.y + v0.z * v0.z + v0.w * v0.w
            + v1.x * v1.x + v1.y * v1.y + v1.z * v1.z + v1.w * v1.w;

    int lo = __builtin_amdgcn_cvt_pk_fp8_f32(v0.x, v0.y, 0, false);
    lo     = __builtin_amdgcn_cvt_pk_fp8_f32(v0.z, v0.w, lo, true);
    int hi = __builtin_amdgcn_cvt_pk_fp8_f32(v1.x, v1.y, 0, false);
    hi     = __builtin_amdgcn_cvt_pk_fp8_f32(v1.z, v1.w, hi, true);
    *(int2*)(dst + (size_t)row * DDIM + lane * 8) = make_int2(lo, hi);

#pragma unroll
    for (int off = 32; off > 0; off >>= 1) s += __shfl_down(s, off, 64);
    if (lane == 0) nrm[row] = s;
}

// ---------------------------------------------------------------------------
// Fused GEMM + RBF epilogue, MX-fp8 (scale = 1.0).
// 128x128 block tile, BK=128, 4 waves (2x2), each wave 4x4 of
// mfma_scale_f32_16x16x128_f8f6f4. global_load_lds width=16 staging with
// XOR chunk-swizzle (chunk ^= row&7) applied on the GLOBAL side so the LDS
// destination stays base + lane*16 (HW requirement) while fragment reads
// spread across all 32 banks (row stride 128 B would otherwise give a
// 16-way conflict).
// ---------------------------------------------------------------------------
__global__ void __launch_bounds__(256)
rbf_gemm(const unsigned char* __restrict__ xb,
         const unsigned char* __restrict__ yb,
         const float* __restrict__ x2, const float* __restrict__ y2,
         const float* __restrict__ gamma, float* __restrict__ out) {
    __shared__ unsigned char As[128 * 128];
    __shared__ unsigned char Bs[128 * 128];

    const int tid  = threadIdx.x;
    const int lane = tid & 63;
    const int w    = tid >> 6;        // wave 0..3
    const int wm   = w & 1;           // wave row (0..1)
    const int wn   = w >> 1;          // wave col (0..1)

    const int bm = blockIdx.x & 63;
    const int bn = blockIdx.x >> 6;
    const int row0 = bm * 128;
    const int col0 = bn * 128;

    f32x4 acc[4][4] = {};

    // staging: each issue stages 8 rows x 128 B; lane L -> row L>>3, LDS chunk L&7
    const int srl = lane >> 3;              // row within 8-row group
    const int sgc = ((lane & 7) ^ srl) * 16;  // swizzled GLOBAL byte chunk

    for (int k0 = 0; k0 < DDIM; k0 += 128) {
#pragma unroll
        for (int i = 0; i < 4; ++i) {
            int rg = w * 32 + i * 8;   // wave-uniform row group (8 rows)
            gload_lds16(xb + (size_t)(row0 + rg + srl) * DDIM + k0 + sgc,
                        As + rg * 128);
            gload_lds16(yb + (size_t)(col0 + rg + srl) * DDIM + k0 + sgc,
                        Bs + rg * 128);
        }
        __syncthreads();

        // fragment loads: lane needs global k-chunks 2g,2g+1 (g = lane>>4)
        // of row r; LDS chunk = global chunk ^ (r & 7), and r&7 == lane&7.
        const int sw = lane & 7;
        const int g2 = (lane >> 4) * 2;
        i32x8 af[4], bfr[4];
#pragma unroll
        for (int mi = 0; mi < 4; ++mi) {
            const unsigned char* base = As + (wm * 64 + mi * 16 + (lane & 15)) * 128;
            i32x4 lo = *(const i32x4*)(base + ((g2    ) ^ sw) * 16);
            i32x4 hi = *(const i32x4*)(base + ((g2 + 1) ^ sw) * 16);
            af[mi] = __builtin_shufflevector(lo, hi, 0, 1, 2, 3, 4, 5, 6, 7);
        }
#pragma unroll
        for (int ni = 0; ni < 4; ++ni) {
            const unsigned char* base = Bs + (wn * 64 + ni * 16 + (lane & 15)) * 128;
            i32x4 lo = *(const i32x4*)(base + ((g2    ) ^ sw) * 16);
            i32x4 hi = *(const i32x4*)(base + ((g2 + 1) ^ sw) * 16);
            bfr[ni] = __builtin_shufflevector(lo, hi, 0, 1, 2, 3, 4, 5, 6, 7);
        }
#pragma unroll
        for (int mi = 0; mi < 4; ++mi)
#pragma unroll
            for (int ni = 0; ni < 4; ++ni)
                acc[mi][ni] = __builtin_amdgcn_mfma_scale_f32_16x16x128_f8f6f4(
                    af[mi], bfr[ni], acc[mi][ni],
                    0, 0,          // cbsz=fp8(e4m3), blgp=fp8(e4m3)
                    0, 0x7F,       // A scale: opsel 0, E8M0 127 = 1.0
                    0, 0x7F);      // B scale
        __syncthreads();
    }

    // Epilogue: out[r][c] = exp(-g * (x2[r] + y2[c] - 2*xy))
    // C/D layout (16x16, shape-determined): col = lane&15, row = (lane>>4)*4 + reg
    const float g = gamma[0];
#pragma unroll
    for (int mi = 0; mi < 4; ++mi) {
        const int rbase = row0 + wm * 64 + mi * 16 + (lane >> 4) * 4;
        float xn[4];
#pragma unroll
        for (int r = 0; r < 4; ++r) xn[r] = x2[rbase + r];
#pragma unroll
        for (int ni = 0; ni < 4; ++ni) {
            const int col = col0 + wn * 64 + ni * 16 + (lane & 15);
            const float yn = y2[col];
            float* op = out + (size_t)rbase * OUTN + col;
#pragma unroll
            for (int r = 0; r < 4; ++r) {
                float s = xn[r] + yn - 2.0f * acc[mi][ni][r];
                op[(size_t)r * OUTN] = __expf(-g * s);
            }
        }
    }
}

extern "C" void kernel_launch(void* const* d_in, const int* in_sizes, int n_in,
                              void* d_out, int out_size, void* d_ws, size_t ws_size,
                              hipStream_t stream) {
    const float* x     = (const float*)d_in[0];
    const float* y     = (const float*)d_in[1];
    const float* gamma = (const float*)d_in[2];
    float* out = (float*)d_out;

    // workspace: xb (4 MB) | yb (4 MB) | x2 (32 KB) | y2 (32 KB)
    char* ws = (char*)d_ws;
    unsigned char* xb = (unsigned char*)ws;
    unsigned char* yb = (unsigned char*)(ws + (size_t)NROWS * DDIM);
    float* x2 = (float*)(ws + (size_t)NROWS * DDIM * 2);
    float* y2 = (float*)(ws + (size_t)NROWS * DDIM * 2 + NROWS * 4);

    rbf_prep<<<4096, 256, 0, stream>>>(x, y, xb, yb, x2, y2);
    rbf_gemm<<<4096, 256, 0, stream>>>(xb, yb, x2, y2, gamma, out);
}